// Round 8
// baseline (1463.918 us; speedup 1.0000x reference)
//
#include <hip/hip_runtime.h>
#include <math.h>

// B=32, R=16384, C=16, IC=16, OC=16, 3 routing iterations.
// x: (B,C,IC) fp32 [8192]; W: (R,C,OC,IC) fp32 [67108864 = 256 MB]; out: (B,C,OC) fp32.
//
// Algebra 1: b after iter2 = <u,v1>, after iter3 = <u,v1+v2> -> no logit array.
// Algebra 2: iter-1 is the same streaming kernel with uniform weights (MODE 0).
//
// R7 result: spill-free at VGPR=44 (launch_bounds(1024,4) -> 64-arch cap law),
// WRITE 2 MB, FETCH 131 MB (W half-L3-resident), 183 us/pass -- but LDS-BW
// bound: bl=2 -> 16 waves re-read each 32 KB tile = 16x amplification = 4.3 GB
// LDS reads/pass (~2x the FMA issue time; VALUBusy 34%, HBM 9%).
// This round: bl=4 at the SAME 64-reg cap by splitting o four ways:
//   8 waves x b-quad; lane = (oq = lane>>4, rl = lane&15); chunk = 32 rows
//   processed as 2 sub-rows/lane. u[4][4]+accE[4][4]+w(16)+addr ~= 58 VGPR.
// Amplification 16x -> 8x (2.1 GB/pass ~= 41 us), FMA ~45 us, HBM 21-41 us,
// at 2 blocks/CU x 8 waves = 4 waves/SIMD.

#define RT 16384

// dot of 4 float4 (VGPR) against 16 scalars (SGPR) -- v_fmac v,s,v is legal.
#define DOT16S(w0,w1,w2,w3,xs) \
  (w0.x*xs[0] + w0.y*xs[1] + w0.z*xs[2] + w0.w*xs[3] + \
   w1.x*xs[4] + w1.y*xs[5] + w1.z*xs[6] + w1.w*xs[7] + \
   w2.x*xs[8] + w2.y*xs[9] + w2.z*xs[10] + w2.w*xs[11] + \
   w3.x*xs[12] + w3.y*xs[13] + w3.z*xs[14] + w3.w*xs[15])

// async global->LDS, 16 B per lane. LDS dest = wave-uniform base + lane*16.
__device__ __forceinline__ void gload_lds16(const void* g, void* l) {
  __builtin_amdgcn_global_load_lds(
      (const __attribute__((address_space(1))) unsigned int*)g,
      (__attribute__((address_space(3))) unsigned int*)l, 16, 0, 0);
}

__device__ __forceinline__ float rfl(float v) {
  return __uint_as_float(__builtin_amdgcn_readfirstlane(__float_as_uint(v)));
}

// ---------------------------------------------------------------------------
// k_v1: v1 = squash(S / R), S = E1[b,c,o] (sum over r of u, from MODE-0 pass)
// ---------------------------------------------------------------------------
__global__ __launch_bounds__(256) void k_v1(const float* __restrict__ E1,
                                            float* __restrict__ v1) {
    int t = blockIdx.x * 256 + threadIdx.x;        // 0..8191
    float s = E1[t] * (1.0f / 16384.0f);
    float ns = s * s;
    #pragma unroll
    for (int d = 1; d < 16; d <<= 1) ns += __shfl_xor(ns, d);
    v1[t] = s * (sqrtf(ns) / (1.0f + ns));
}

// k_vsum: v2 = squash(E/Z); vsum = v1 + v2
__global__ __launch_bounds__(256) void k_vsum(const float* __restrict__ E,
                                              const float* __restrict__ Z,
                                              const float* __restrict__ v1,
                                              float* __restrict__ vsum) {
    int t = blockIdx.x * 256 + threadIdx.x;
    float s = E[t] / Z[t >> 4];
    float ns = s * s;
    #pragma unroll
    for (int d = 1; d < 16; d <<= 1) ns += __shfl_xor(ns, d);
    vsum[t] = v1[t] + s * (sqrtf(ns) / (1.0f + ns));
}

// k_vout: final v = squash(E/Z) -> out
__global__ __launch_bounds__(256) void k_vout(const float* __restrict__ E,
                                              const float* __restrict__ Z,
                                              float* __restrict__ dst) {
    int t = blockIdx.x * 256 + threadIdx.x;
    float s = E[t] / Z[t >> 4];
    float ns = s * s;
    #pragma unroll
    for (int d = 1; d < 16; d <<= 1) ns += __shfl_xor(ns, d);
    dst[t] = s * (sqrtf(ns) / (1.0f + ns));
}

// ---------------------------------------------------------------------------
// k_route<MODE,REV>: one W-streaming pass.
//   u[o] = sum_i W[r,c,o,i]*x[b,c,i]
//   MODE 0: E[b,c,o] += u[o]                        (uniform routing, iter 1)
//   MODE 1: e = exp(<u,v>); E += e*u; Z += e        (iters 2,3)
// Block 512 = 8 waves; wave wv owns b in {4wv..4wv+3}.
// Lane: oq = lane>>4 = o-quarter (o = oq*4+oo); rl = lane&15.
// Chunk = 32 rows = 2 sub-rows per lane (row = sub*16 + rl); 8 chunks/tile;
// 2 x 32 KB LDS double buffer, prefetch-then-compute (R7-proven schedule).
// LDS float4-XOR swizzle: slot rs*64+l holds row rs's float4 (l^rs); read
// addr slot = row*64 + ((o4+q)^row).  Per read-instr the 64 lanes distribute
// 8 per bank-quad (low3 = ((4oo+q)^row)&7: 8 values x (2 rl x 4 oq)) ->
// exactly 8 words/bank = the conflict-free wave64-b128 minimum.
// Staging source pre-swizzled, LDS dest linear (both-sides-or-neither rule).
// Lv join: part + shfl_xor(16) + shfl_xor(32) sums the 4 o-quarters; e is
// replicated in all 4 quarter-groups (needed for accE anyway).
// v lives in a 2 KB LDS broadcast table (NOT registers) to hold the ~58-reg
// live set under the 64-arch cap of launch_bounds(512,4) (spill-free law, R7).
// ---------------------------------------------------------------------------
template <int MODE, int REV>
__global__ __launch_bounds__(512, 4)
void k_route(const float* __restrict__ W,
             const float* __restrict__ x,
             const float* __restrict__ v,
             float* __restrict__ E,
             float* __restrict__ Z) {
    __shared__ float4 Wl[2][32 * 64];              // 2 x 32 KB double buffer
    __shared__ float Vl[512];                      // v broadcast table (2 KB)
    const int c = blockIdx.y;
    const int bx = REV ? (63 - (int)blockIdx.x) : (int)blockIdx.x;
    const int r0 = bx * 256;
    const int tid = threadIdx.x;
    const int wv = __builtin_amdgcn_readfirstlane(tid >> 6);   // [0,8)
    const int lane = tid & 63;
    const int oq = lane >> 4;                      // o-quarter
    const int rl = lane & 15;                      // row-lane

    const float4* W4c = (const float4*)W + c * 64; // + r*1024 + j

    if (MODE)                                      // Vl[b*16+o] = v[b,c,o]
        Vl[tid] = v[(tid >> 4) * 256 + c * 16 + (tid & 15)];

    // x rows for this wave's 4 b's -> SGPRs (wave-uniform)
    float xs[4][16];
    #pragma unroll
    for (int bl = 0; bl < 4; ++bl) {
        const float* xb = x + ((wv * 4 + bl) * 16 + c) * 16;
        #pragma unroll
        for (int i = 0; i < 16; ++i) xs[bl][i] = rfl(xb[i]);
    }

    float accE[4][4];
    float accZ[4] = {0.f, 0.f, 0.f, 0.f};
    #pragma unroll
    for (int bl = 0; bl < 4; ++bl)
        #pragma unroll
        for (int oo = 0; oo < 4; ++oo) accE[bl][oo] = 0.f;

    // stage chunk 0: wave wv stages rows {k*8+wv}; lane l -> slot rs*64+l,
    // global source pre-swizzled: float4 (l ^ rs) of the row.
    #pragma unroll
    for (int k = 0; k < 4; ++k) {
        int rs = k * 8 + wv;
        gload_lds16(W4c + (size_t)(r0 + rs) * 1024 + (lane ^ rs), &Wl[0][rs * 64]);
    }
    __syncthreads();                               // drains vmcnt(0) + Vl ready

    #pragma unroll
    for (int ch = 0; ch < 8; ++ch) {
        if (ch < 7) {                              // issue next chunk's loads first
            #pragma unroll
            for (int k = 0; k < 4; ++k) {
                int rs = k * 8 + wv;
                gload_lds16(W4c + (size_t)(r0 + (ch + 1) * 32 + rs) * 1024 + (lane ^ rs),
                            &Wl[(ch + 1) & 1][rs * 64]);
            }
        }
        const float4* Wb = Wl[ch & 1];

        #pragma unroll
        for (int sub = 0; sub < 2; ++sub) {
            const int row = sub * 16 + rl;
            float u[4][4];
            #pragma unroll
            for (int oo = 0; oo < 4; ++oo) {
                int o4 = (oq * 4 + oo) * 4;
                float4 w0 = Wb[row * 64 + ((o4 + 0) ^ row)];
                float4 w1 = Wb[row * 64 + ((o4 + 1) ^ row)];
                float4 w2 = Wb[row * 64 + ((o4 + 2) ^ row)];
                float4 w3 = Wb[row * 64 + ((o4 + 3) ^ row)];
                #pragma unroll
                for (int bl = 0; bl < 4; ++bl)
                    u[bl][oo] = DOT16S(w0, w1, w2, w3, xs[bl]);
            }

            #pragma unroll
            for (int bl = 0; bl < 4; ++bl) {
                if (MODE) {
                    const float* vb = &Vl[(wv * 4 + bl) * 16 + oq * 4];
                    float part = 0.f;
                    #pragma unroll
                    for (int oo = 0; oo < 4; ++oo) part += u[bl][oo] * vb[oo];
                    float Lv = part + __shfl_xor(part, 16);
                    Lv += __shfl_xor(Lv, 32);                  // join 4 o-quarters
                    float e = __expf(Lv);
                    accZ[bl] += e;
                    #pragma unroll
                    for (int oo = 0; oo < 4; ++oo) accE[bl][oo] += e * u[bl][oo];
                } else {
                    #pragma unroll
                    for (int oo = 0; oo < 4; ++oo) accE[bl][oo] += u[bl][oo];
                }
            }
        }
        __syncthreads();   // barrier + vmcnt(0) drain of loads issued pre-compute
    }

    // Reduce accE over the 16 row-lanes (butterfly d<16 stays within the
    // 16-lane group, so each o-quarter reduces its own o-range).
    float va = 0.f;
    #pragma unroll
    for (int bl = 0; bl < 4; ++bl) {
        #pragma unroll
        for (int oo = 0; oo < 4; ++oo) {
            float t = accE[bl][oo];
            #pragma unroll
            for (int d = 1; d < 16; d <<= 1) t += __shfl_xor(t, d);
            if (rl == bl * 4 + oo) va = t;
        }
    }
    {   // every lane writes exactly one (b,o): 4 bl x 16 o per wave
        int b = wv * 4 + (rl >> 2);
        int o = oq * 4 + (rl & 3);
        atomicAdd(&E[b * 256 + c * 16 + o], va);
    }
    if (MODE) {
        // accZ identical across the 4 o-quarter groups; reduce over rl, use oq=0
        float vz = 0.f;
        #pragma unroll
        for (int bl = 0; bl < 4; ++bl) {
            float t = accZ[bl];
            #pragma unroll
            for (int d = 1; d < 16; d <<= 1) t += __shfl_xor(t, d);
            if (lane == bl) vz = t;                // oq=0, rl=bl
        }
        if (lane < 4) atomicAdd(&Z[(wv * 4 + lane) * 16 + c], vz);
    }
}

// ---------------------------------------------------------------------------
// launch
// ---------------------------------------------------------------------------
extern "C" void kernel_launch(void* const* d_in, const int* in_sizes, int n_in,
                              void* d_out, int out_size, void* d_ws, size_t ws_size,
                              hipStream_t stream) {
    const float* x = (const float*)d_in[0];        // 8192 floats
    const float* W = (const float*)d_in[1];        // 67108864 floats (256 MB)
    float* out = (float*)d_out;                    // 8192 floats
    float* ws = (float*)d_ws;

    float* E1   = ws + 0;          // 8192  (S = sum_r u)
    float* E2   = ws + 8192;       // 8192
    float* Z2   = ws + 16384;      // 512
    float* E3   = ws + 16896;      // 8192
    float* Z3   = ws + 25088;      // 512   (zeroed region ends at 25600)
    float* v1   = ws + 25600;      // 8192
    float* vsum = ws + 33792;      // 8192

    hipMemsetAsync(ws, 0, 25600 * sizeof(float), stream);

    // iter 1: S = sum_r u (uniform routing), W pass 1 (forward r)
    k_route<0, 0><<<dim3(64, 16), 512, 0, stream>>>(W, x, v1, E1, Z2);
    k_v1<<<32, 256, 0, stream>>>(E1, v1);          // v1 = squash(S/R)

    // iter 2: logits = <u, v1>, W pass 2 (reverse r for L3 tail reuse)
    k_route<1, 1><<<dim3(64, 16), 512, 0, stream>>>(W, x, v1, E2, Z2);
    k_vsum<<<32, 256, 0, stream>>>(E2, Z2, v1, vsum);  // vsum = v1 + squash(E2/Z2)

    // iter 3: logits = <u, v1+v2>, W pass 3 (forward r)
    k_route<1, 0><<<dim3(64, 16), 512, 0, stream>>>(W, x, vsum, E3, Z3);
    k_vout<<<32, 256, 0, stream>>>(E3, Z3, out);
}

// Round 9
// 807.654 us; speedup vs baseline: 1.8126x; 1.8126x over previous
//
#include <hip/hip_runtime.h>
#include <math.h>

// B=32, R=16384, C=16, IC=16, OC=16, 3 routing iterations.
// x: (B,C,IC) fp32 [8192]; W: (R,C,OC,IC) fp32 [67108864 = 256 MB]; out: (B,C,OC) fp32.
//
// Algebra 1: b after iter2 = <u,v1>, after iter3 = <u,v1+v2> -> no logit array.
// Algebra 2: iter-1 is the same streaming kernel with uniform weights (MODE 0).
//
// R1-R8 lesson: with VALU dot-products, every wave must re-read the whole W
// tile from LDS (amplification = 32/bl) and bl is pinned by the register file
// (64-arch cap at 4 waves/EU, 128 at 2) -> either LDS-BW-bound (R7: 183 us/
// pass) or spill-bound (R2/3/5/6/8). MFMA escape: put all 32 b in the MFMA
// N-operand -> W read ONCE per element (amplification 1x), accumulators in
// AGPRs (no VALU pressure). fp32 fidelity via 2-term fp16 split with scaled
// low word: W = Wh + 2^-11*Wl', x = Xh + 2^-11*Xl'; u = hh + 2^-11*(hl+lh),
// residual ~2^-22 (~fp32). 6 MFMAs/route ~ 13 us/pass << HBM 41 us.

typedef _Float16 half8_t __attribute__((ext_vector_type(8)));
typedef float f32x4_t __attribute__((ext_vector_type(4)));

// async global->LDS, 16 B per lane. LDS dest = wave-uniform base + lane*16.
__device__ __forceinline__ void gload_lds16(const void* g, void* l) {
  __builtin_amdgcn_global_load_lds(
      (const __attribute__((address_space(1))) unsigned int*)g,
      (__attribute__((address_space(3))) unsigned int*)l, 16, 0, 0);
}

// ---------------------------------------------------------------------------
// k_v1: v1 = squash(S / R), S = E1[b,c,o] (sum over r of u, from MODE-0 pass)
// ---------------------------------------------------------------------------
__global__ __launch_bounds__(256) void k_v1(const float* __restrict__ E1,
                                            float* __restrict__ v1) {
    int t = blockIdx.x * 256 + threadIdx.x;        // 0..8191
    float s = E1[t] * (1.0f / 16384.0f);
    float ns = s * s;
    #pragma unroll
    for (int d = 1; d < 16; d <<= 1) ns += __shfl_xor(ns, d);
    v1[t] = s * (sqrtf(ns) / (1.0f + ns));
}

// k_vsum: v2 = squash(E/Z); vsum = v1 + v2
__global__ __launch_bounds__(256) void k_vsum(const float* __restrict__ E,
                                              const float* __restrict__ Z,
                                              const float* __restrict__ v1,
                                              float* __restrict__ vsum) {
    int t = blockIdx.x * 256 + threadIdx.x;
    float s = E[t] / Z[t >> 4];
    float ns = s * s;
    #pragma unroll
    for (int d = 1; d < 16; d <<= 1) ns += __shfl_xor(ns, d);
    vsum[t] = v1[t] + s * (sqrtf(ns) / (1.0f + ns));
}

// k_vout: final v = squash(E/Z) -> out
__global__ __launch_bounds__(256) void k_vout(const float* __restrict__ E,
                                              const float* __restrict__ Z,
                                              float* __restrict__ dst) {
    int t = blockIdx.x * 256 + threadIdx.x;
    float s = E[t] / Z[t >> 4];
    float ns = s * s;
    #pragma unroll
    for (int d = 1; d < 16; d <<= 1) ns += __shfl_xor(ns, d);
    dst[t] = s * (sqrtf(ns) / (1.0f + ns));
}

// ---------------------------------------------------------------------------
// k_route<MODE,REV>: one W-streaming pass via MFMA.
// Block 512 = 8 waves; grid (64 bx, 16 c). Per chunk of 32 routes (32 KB LDS,
// double-buffered 64 KB, prefetch-then-compute = R7-proven schedule), wave wv
// computes routes {rr*8+wv}. Per route r:
//   A = W[r,c][o=16][i=16] (K=32 zero-padded), B = x[i][b] (2 b-halves),
//   D[o][b] = u. 3 MFMAs per b-half: hh -> acc1; hl, lh -> acc2 (2^11-scaled).
//   u = acc1 + acc2/2048.  C/D: lane -> (b = lane&15, o = (lane>>4)*4 + reg).
//   Lv[b] = sum_o u*v = 4 lane-local fma + shfl_xor(16) + shfl_xor(32);
//   e = exp(Lv); accE[o][b] += e*u (lane-local, 8 regs); accZ += e.
// A-frag LDS layout: row r stored as 64 float4s at pos p:
//   p<32 : (kb=p>>4, o=p&15) -> W[r,c][o][8kb + 0..3]
//   p>=32: same (o,kb) -> W[r,c][o][8kb + 4..7]
// so lane l reads pos (l&31) and 32+(l&31): 32 distinct addrs + 2-way
// broadcast = conflict-free. Staged by gload_lds16 with the per-lane source
// offset so4 (LDS dest linear, source permuted: both-sides-or-neither rule).
// MODE 0: accE += u (uniform routing). REV: reverse bx for L3 tail reuse.
// ---------------------------------------------------------------------------
template <int MODE, int REV>
__global__ __launch_bounds__(512, 1)
void k_route(const float* __restrict__ W,
             const float* __restrict__ x,
             const float* __restrict__ v,
             float* __restrict__ E,
             float* __restrict__ Z) {
    __shared__ float4 Wl[2][32 * 64];              // 2 x 32 KB double buffer
    const int c = blockIdx.y;
    const int bx = REV ? (63 - (int)blockIdx.x) : (int)blockIdx.x;
    const int r0 = bx * 256;
    const int tid = threadIdx.x;
    const int wv = tid >> 6;                       // [0,8)
    const int lane = tid & 63;
    const int bcol = lane & 15;                    // b within half
    const int rowg = lane >> 4;                    // k-block (A/B) / o-group (C/D)

    const float4* W4 = (const float4*)W;
    // per-lane source float4 offset within a 64-float4 W row (A-frag order)
    const int p = lane & 31;
    const int so4 = (p & 15) * 4 + ((p >> 4) & 1) * 2 + (lane >> 5);

    // ---- B fragments from x (per c, constant across chunks) ----
    half8_t Bh[2], Bl[2];
    #pragma unroll
    for (int bh = 0; bh < 2; ++bh) {
        float xv[8] = {0.f,0.f,0.f,0.f,0.f,0.f,0.f,0.f};
        if (rowg < 2) {
            const float4* xb = (const float4*)x + ((bh * 16 + bcol) * 16 + c) * 4 + rowg * 2;
            float4 a0 = xb[0], a1 = xb[1];
            xv[0]=a0.x; xv[1]=a0.y; xv[2]=a0.z; xv[3]=a0.w;
            xv[4]=a1.x; xv[5]=a1.y; xv[6]=a1.z; xv[7]=a1.w;
        }
        #pragma unroll
        for (int j = 0; j < 8; ++j) {
            _Float16 h = (_Float16)xv[j];
            Bh[bh][j] = h;
            Bl[bh][j] = (_Float16)((xv[j] - (float)h) * 2048.0f);
        }
    }
    // v slice for this lane's (b x o) outputs
    float vv[2][4];
    if (MODE) {
        #pragma unroll
        for (int bh = 0; bh < 2; ++bh)
            #pragma unroll
            for (int j = 0; j < 4; ++j)
                vv[bh][j] = v[((bh * 16 + bcol) * 16 + c) * 16 + rowg * 4 + j];
    }

    float accE[2][4];
    float accZ[2] = {0.f, 0.f};
    #pragma unroll
    for (int bh = 0; bh < 2; ++bh)
        #pragma unroll
        for (int j = 0; j < 4; ++j) accE[bh][j] = 0.f;

    // stage chunk 0: wave wv stages rows {k*8+wv}
    #pragma unroll
    for (int k = 0; k < 4; ++k) {
        int rs = k * 8 + wv;
        gload_lds16(W4 + ((size_t)(r0 + rs) * 16 + c) * 64 + so4, &Wl[0][rs * 64]);
    }
    __syncthreads();                               // drains vmcnt(0)

    const f32x4_t z4 = {0.f, 0.f, 0.f, 0.f};

    #pragma unroll
    for (int ch = 0; ch < 8; ++ch) {
        if (ch < 7) {                              // issue next chunk's loads first
            #pragma unroll
            for (int k = 0; k < 4; ++k) {
                int rs = k * 8 + wv;
                gload_lds16(W4 + ((size_t)(r0 + (ch + 1) * 32 + rs) * 16 + c) * 64 + so4,
                            &Wl[(ch + 1) & 1][rs * 64]);
            }
        }
        const float4* Wb = Wl[ch & 1];

        #pragma unroll
        for (int rr = 0; rr < 4; ++rr) {
            const int rs = rr * 8 + wv;            // this wave's route in chunk
            float4 wa = Wb[rs * 64 + (lane & 31)];
            float4 wc = Wb[rs * 64 + 32 + (lane & 31)];
            float wf[8] = {wa.x, wa.y, wa.z, wa.w, wc.x, wc.y, wc.z, wc.w};
            half8_t Ah, Al;
            #pragma unroll
            for (int j = 0; j < 8; ++j) {
                float w0 = (lane < 32) ? wf[j] : 0.f;
                _Float16 h = (_Float16)w0;
                Ah[j] = h;
                Al[j] = (_Float16)((w0 - (float)h) * 2048.0f);
            }
            // 3-MFMA split per b-half: u = hh + (hl + lh)/2048
            f32x4_t a1_0 = __builtin_amdgcn_mfma_f32_16x16x32_f16(Ah, Bh[0], z4, 0, 0, 0);
            f32x4_t a2_0 = __builtin_amdgcn_mfma_f32_16x16x32_f16(Ah, Bl[0], z4, 0, 0, 0);
            a2_0 = __builtin_amdgcn_mfma_f32_16x16x32_f16(Al, Bh[0], a2_0, 0, 0, 0);
            f32x4_t a1_1 = __builtin_amdgcn_mfma_f32_16x16x32_f16(Ah, Bh[1], z4, 0, 0, 0);
            f32x4_t a2_1 = __builtin_amdgcn_mfma_f32_16x16x32_f16(Ah, Bl[1], z4, 0, 0, 0);
            a2_1 = __builtin_amdgcn_mfma_f32_16x16x32_f16(Al, Bh[1], a2_1, 0, 0, 0);

            float u0[4], u1[4];
            #pragma unroll
            for (int j = 0; j < 4; ++j) {
                u0[j] = a1_0[j] + a2_0[j] * (1.0f / 2048.0f);
                u1[j] = a1_1[j] + a2_1[j] * (1.0f / 2048.0f);
            }

            if (MODE) {
                float p0 = u0[0]*vv[0][0] + u0[1]*vv[0][1] + u0[2]*vv[0][2] + u0[3]*vv[0][3];
                float p1 = u1[0]*vv[1][0] + u1[1]*vv[1][1] + u1[2]*vv[1][2] + u1[3]*vv[1][3];
                p0 += __shfl_xor(p0, 16);  p0 += __shfl_xor(p0, 32);
                p1 += __shfl_xor(p1, 16);  p1 += __shfl_xor(p1, 32);
                float e0 = __expf(p0), e1 = __expf(p1);
                accZ[0] += e0;  accZ[1] += e1;
                #pragma unroll
                for (int j = 0; j < 4; ++j) {
                    accE[0][j] += e0 * u0[j];
                    accE[1][j] += e1 * u1[j];
                }
            } else {
                #pragma unroll
                for (int j = 0; j < 4; ++j) {
                    accE[0][j] += u0[j];
                    accE[1][j] += u1[j];
                }
            }
        }
        __syncthreads();   // barrier + vmcnt(0) drain of loads issued pre-compute
    }

    // ---- cross-wave reduction via LDS (reuse Wl[0] region, 17 KB) ----
    float* red = (float*)Wl;
    #pragma unroll
    for (int bh = 0; bh < 2; ++bh) {
        // lane's 4 o's are consecutive -> one float4 store, conflict-free
        float4 t4 = make_float4(accE[bh][0], accE[bh][1], accE[bh][2], accE[bh][3]);
        *(float4*)&red[wv * 512 + (bh * 16 + bcol) * 16 + rowg * 4] = t4;
    }
    if (MODE && rowg == 0) {                       // e replicated x4 over rowg
        red[4096 + wv * 32 + bcol]      = accZ[0];
        red[4096 + wv * 32 + 16 + bcol] = accZ[1];
    }
    __syncthreads();
    {   // tid in [0,512): slot = bfull*16 + o
        float s = 0.f;
        #pragma unroll
        for (int w2 = 0; w2 < 8; ++w2) s += red[w2 * 512 + tid];
        int bfull = tid >> 4, o = tid & 15;
        atomicAdd(&E[bfull * 256 + c * 16 + o], s);
    }
    if (MODE && tid < 32) {
        float s = 0.f;
        #pragma unroll
        for (int w2 = 0; w2 < 8; ++w2) s += red[4096 + w2 * 32 + tid];
        atomicAdd(&Z[tid * 16 + c], s);
    }
}

// ---------------------------------------------------------------------------
// launch
// ---------------------------------------------------------------------------
extern "C" void kernel_launch(void* const* d_in, const int* in_sizes, int n_in,
                              void* d_out, int out_size, void* d_ws, size_t ws_size,
                              hipStream_t stream) {
    const float* x = (const float*)d_in[0];        // 8192 floats
    const float* W = (const float*)d_in[1];        // 67108864 floats (256 MB)
    float* out = (float*)d_out;                    // 8192 floats
    float* ws = (float*)d_ws;

    float* E1   = ws + 0;          // 8192  (S = sum_r u)
    float* E2   = ws + 8192;       // 8192
    float* Z2   = ws + 16384;      // 512
    float* E3   = ws + 16896;      // 8192
    float* Z3   = ws + 25088;      // 512   (zeroed region ends at 25600)
    float* v1   = ws + 25600;      // 8192
    float* vsum = ws + 33792;      // 8192

    hipMemsetAsync(ws, 0, 25600 * sizeof(float), stream);

    // iter 1: S = sum_r u (uniform routing), W pass 1 (forward r)
    k_route<0, 0><<<dim3(64, 16), 512, 0, stream>>>(W, x, v1, E1, Z2);
    k_v1<<<32, 256, 0, stream>>>(E1, v1);          // v1 = squash(S/R)

    // iter 2: logits = <u, v1>, W pass 2 (reverse r for L3 tail reuse)
    k_route<1, 1><<<dim3(64, 16), 512, 0, stream>>>(W, x, v1, E2, Z2);
    k_vsum<<<32, 256, 0, stream>>>(E2, Z2, v1, vsum);  // vsum = v1 + squash(E2/Z2)

    // iter 3: logits = <u, v1+v2>, W pass 3 (forward r)
    k_route<1, 0><<<dim3(64, 16), 512, 0, stream>>>(W, x, vsum, E3, Z3);
    k_vout<<<32, 256, 0, stream>>>(E3, Z3, out);
}

// Round 10
// 488.851 us; speedup vs baseline: 2.9946x; 1.6521x over previous
//
#include <hip/hip_runtime.h>
#include <math.h>

// B=32, R=16384, C=16, IC=16, OC=16, 3 routing iterations.
// x: (B,C,IC) fp32 [8192]; W: (R,C,OC,IC) fp32 [67108864 = 256 MB]; out: (B,C,OC) fp32.
//
// Algebra 1: b after iter2 = <u,v1>, after iter3 = <u,v1+v2> -> no logit array.
// Algebra 2: iter-1 is the same streaming kernel with uniform weights (MODE 0).
//
// R9 lesson: MFMA removes W reuse entirely (each W element feeds ONE lane's
// A-fragment) -> LDS staging is pointless. Stream W global->VGPR directly:
// no barriers, no dbuf, no bank conflicts, small live set (R9's 500 MB of
// scratch-spill WRITE came from the unrolled LDS+6-accumulator schedule).
//
// This round: mfma_f32_32x32x16_f16 packs TWO routes (M=32 = 2x o16) x all
// 32 b (N=32), K=16=IC exactly (no zero pad). 3 MFMAs per pair (2-term fp16
// split: u = hh + (hl+lh)/2048, residual ~2^-22 ~= fp32; R9 measured 4.8e-7).
// D-layout (HW-verified): lane -> b=lane&31; reg j -> row=(j&3)+8*(j>>2)+
// 4*(lane>>5); row<16 = route-even o=row, row>=16 = route-odd o=row-16.
// MODE 0 carries the MFMA accumulators across all pairs (no per-pair VALU).
// Floors/pass: HBM ~41 us >> VALU ~11 us, MFMA ~6 us -> HBM-bound by design.

typedef _Float16 half8_t __attribute__((ext_vector_type(8)));
typedef float f32x16_t __attribute__((ext_vector_type(16)));

// ---------------------------------------------------------------------------
// k_v1: v1 = squash(S / R), S = E1[b,c,o] (sum over r of u, from MODE-0 pass)
// ---------------------------------------------------------------------------
__global__ __launch_bounds__(256) void k_v1(const float* __restrict__ E1,
                                            float* __restrict__ v1) {
    int t = blockIdx.x * 256 + threadIdx.x;        // 0..8191
    float s = E1[t] * (1.0f / 16384.0f);
    float ns = s * s;
    #pragma unroll
    for (int d = 1; d < 16; d <<= 1) ns += __shfl_xor(ns, d);
    v1[t] = s * (sqrtf(ns) / (1.0f + ns));
}

// k_vsum: v2 = squash(E/Z); vsum = v1 + v2
__global__ __launch_bounds__(256) void k_vsum(const float* __restrict__ E,
                                              const float* __restrict__ Z,
                                              const float* __restrict__ v1,
                                              float* __restrict__ vsum) {
    int t = blockIdx.x * 256 + threadIdx.x;
    float s = E[t] / Z[t >> 4];
    float ns = s * s;
    #pragma unroll
    for (int d = 1; d < 16; d <<= 1) ns += __shfl_xor(ns, d);
    vsum[t] = v1[t] + s * (sqrtf(ns) / (1.0f + ns));
}

// k_vout: final v = squash(E/Z) -> out
__global__ __launch_bounds__(256) void k_vout(const float* __restrict__ E,
                                              const float* __restrict__ Z,
                                              float* __restrict__ dst) {
    int t = blockIdx.x * 256 + threadIdx.x;
    float s = E[t] / Z[t >> 4];
    float ns = s * s;
    #pragma unroll
    for (int d = 1; d < 16; d <<= 1) ns += __shfl_xor(ns, d);
    dst[t] = s * (sqrtf(ns) / (1.0f + ns));
}

// ---------------------------------------------------------------------------
// k_route<MODE,REV>: one W-streaming pass via paired-route MFMA, LDS-free
// main loop.  Block 512 = 8 waves; grid (64 bx, 16 c).  Wave wv owns routes
// r0+wv*32 .. +31 = 16 pairs.  Per pair p (routes 2p, 2p+1):
//   A[m=32][k=16]: m<16 -> route-even o=m; m>=16 -> route-odd o=m-16.
//     lane l holds m=l&31, k=8*(l>>5)+j  -> 2 global float4 loads per lane
//     from row (2p + ((l>>4)&1)) at float (l&15)*16 + (l>>5)*8.
//   B[k=16][n=32]: n = b = l&31, k = 8*(l>>5)+j (from x, loaded once).
//   3 MFMAs: a1=hh, a2=hl+lh; u = a1 + a2/2048.
//   MODE 1: Lv per parity = 8 lane-local fma + shfl_xor(32); e = exp(Lv);
//           accE[16] += e*u (lane-local); accZ += e.
//   MODE 0: a1,a2 carry across all pairs (C-in=C-out); extract once at end.
// Prefetch depth 2 pairs (4 KB/wave in flight, covers ~900-cyc cold HBM);
// rolled loop (#pragma unroll 2) to avoid R9's unroll-hoist register bloat.
// REV: reverse bx walk for L3 tail reuse between consecutive passes.
// ---------------------------------------------------------------------------
template <int MODE, int REV>
__global__ __launch_bounds__(512, 2)
void k_route(const float* __restrict__ W,
             const float* __restrict__ x,
             const float* __restrict__ v,
             float* __restrict__ E,
             float* __restrict__ Z) {
    __shared__ float red[8 * 512 + 256];           // 17 KB epilogue scratch
    const int c = blockIdx.y;
    const int bx = REV ? (63 - (int)blockIdx.x) : (int)blockIdx.x;
    const int r0 = bx * 256;
    const int tid = threadIdx.x;
    const int wv = tid >> 6;                       // [0,8)
    const int lane = tid & 63;
    const int b = lane & 31;                       // batch (N-col / D-col)
    const int kh = lane >> 5;                      // k-half

    // ---- B fragments from x (loaded once; fp16 split) ----
    half8_t Bh, Bl;
    {
        const float4* xb = (const float4*)(x + (b * 16 + c) * 16) + kh * 2;
        float4 x0 = xb[0], x1 = xb[1];
        float xv[8] = {x0.x, x0.y, x0.z, x0.w, x1.x, x1.y, x1.z, x1.w};
        #pragma unroll
        for (int j = 0; j < 8; ++j) {
            _Float16 h = (_Float16)xv[j];
            Bh[j] = h;
            Bl[j] = (_Float16)((xv[j] - (float)h) * 2048.0f);
        }
    }
    // v slice for this lane: o in {4kh..4kh+3} u {8+4kh..11+4kh}
    float vv[8];
    if (MODE) {
        const float4* vb = (const float4*)(v + (b * 16 + c) * 16);
        float4 v0 = vb[kh], v1 = vb[2 + kh];
        vv[0]=v0.x; vv[1]=v0.y; vv[2]=v0.z; vv[3]=v0.w;
        vv[4]=v1.x; vv[5]=v1.y; vv[6]=v1.z; vv[7]=v1.w;
    }

    f32x16_t a1 = {0.f,0.f,0.f,0.f,0.f,0.f,0.f,0.f,
                   0.f,0.f,0.f,0.f,0.f,0.f,0.f,0.f};
    f32x16_t a2 = a1;
    const f32x16_t z16 = a1;
    float accE[16];
    #pragma unroll
    for (int j = 0; j < 16; ++j) accE[j] = 0.f;
    float accZ0 = 0.f, accZ1 = 0.f;

    // per-lane W pointer: pair p -> route r0 + wv*32 + 2p + ((lane>>4)&1)
    const int rsel = (lane >> 4) & 1;
    const float4* wp = (const float4*)W
        + ((size_t)(r0 + wv * 32 + rsel) * 16 + c) * 64
        + (lane & 15) * 4 + kh * 2;
    const size_t PSTR = 2 * 16 * 64;               // 2 routes in float4s

    float4 n0a = wp[0], n0b = wp[1];               // prefetch pair 0
    float4 n1a = wp[PSTR], n1b = wp[PSTR + 1];     // prefetch pair 1

    #pragma unroll 2
    for (int p = 0; p < 16; ++p) {
        float4 wa = n0a, wb = n0b;
        n0a = n1a; n0b = n1b;
        if (p + 2 < 16) {                          // issue pair p+2 loads
            const float4* np = wp + (size_t)(p + 2) * PSTR;
            n1a = np[0]; n1b = np[1];
        }
        float wf[8] = {wa.x, wa.y, wa.z, wa.w, wb.x, wb.y, wb.z, wb.w};
        half8_t Ah, Al;
        #pragma unroll
        for (int j = 0; j < 8; ++j) {
            _Float16 h = (_Float16)wf[j];
            Ah[j] = h;
            Al[j] = (_Float16)((wf[j] - (float)h) * 2048.0f);
        }
        if (MODE) {
            f32x16_t t1 = __builtin_amdgcn_mfma_f32_32x32x16_f16(Ah, Bh, z16, 0, 0, 0);
            f32x16_t t2 = __builtin_amdgcn_mfma_f32_32x32x16_f16(Ah, Bl, z16, 0, 0, 0);
            t2 = __builtin_amdgcn_mfma_f32_32x32x16_f16(Al, Bh, t2, 0, 0, 0);
            float u[16];
            #pragma unroll
            for (int j = 0; j < 16; ++j) u[j] = t1[j] + t2[j] * (1.0f / 2048.0f);
            float pe = 0.f, po = 0.f;
            #pragma unroll
            for (int rb = 0; rb < 4; ++rb) {
                pe += u[rb] * vv[rb] + u[4 + rb] * vv[4 + rb];
                po += u[8 + rb] * vv[rb] + u[12 + rb] * vv[4 + rb];
            }
            pe += __shfl_xor(pe, 32);              // join k-halves (o-halves)
            po += __shfl_xor(po, 32);
            float e0 = __expf(pe), e1 = __expf(po);
            accZ0 += e0;  accZ1 += e1;
            #pragma unroll
            for (int j = 0; j < 8; ++j)  accE[j] += e0 * u[j];
            #pragma unroll
            for (int j = 8; j < 16; ++j) accE[j] += e1 * u[j];
        } else {
            a1 = __builtin_amdgcn_mfma_f32_32x32x16_f16(Ah, Bh, a1, 0, 0, 0);
            a2 = __builtin_amdgcn_mfma_f32_32x32x16_f16(Ah, Bl, a2, 0, 0, 0);
            a2 = __builtin_amdgcn_mfma_f32_32x32x16_f16(Al, Bh, a2, 0, 0, 0);
        }
    }
    if (!MODE) {
        #pragma unroll
        for (int j = 0; j < 16; ++j) accE[j] = a1[j] + a2[j] * (1.0f / 2048.0f);
    }

    // fold route parities: contribution to E[b,c,o]:
    //   o = 4kh+rb    <- accE[rb]   + accE[8+rb]
    //   o = 8+4kh+rb  <- accE[4+rb] + accE[12+rb]
    float4 e0 = make_float4(accE[0] + accE[8],  accE[1] + accE[9],
                            accE[2] + accE[10], accE[3] + accE[11]);
    float4 e1 = make_float4(accE[4] + accE[12], accE[5] + accE[13],
                            accE[6] + accE[14], accE[7] + accE[15]);
    *(float4*)&red[wv * 512 + b * 16 + 4 * kh]     = e0;
    *(float4*)&red[wv * 512 + b * 16 + 8 + 4 * kh] = e1;
    if (MODE && kh == 0) red[4096 + wv * 32 + b] = accZ0 + accZ1;
    __syncthreads();
    {
        float s = 0.f;
        #pragma unroll
        for (int w2 = 0; w2 < 8; ++w2) s += red[w2 * 512 + tid];
        atomicAdd(&E[(tid >> 4) * 256 + c * 16 + (tid & 15)], s);
    }
    if (MODE && tid < 32) {
        float sz = 0.f;
        #pragma unroll
        for (int w2 = 0; w2 < 8; ++w2) sz += red[4096 + w2 * 32 + tid];
        atomicAdd(&Z[tid * 16 + c], sz);
    }
}

// ---------------------------------------------------------------------------
// launch
// ---------------------------------------------------------------------------
extern "C" void kernel_launch(void* const* d_in, const int* in_sizes, int n_in,
                              void* d_out, int out_size, void* d_ws, size_t ws_size,
                              hipStream_t stream) {
    const float* x = (const float*)d_in[0];        // 8192 floats
    const float* W = (const float*)d_in[1];        // 67108864 floats (256 MB)
    float* out = (float*)d_out;                    // 8192 floats
    float* ws = (float*)d_ws;

    float* E1   = ws + 0;          // 8192  (S = sum_r u)
    float* E2   = ws + 8192;       // 8192
    float* Z2   = ws + 16384;      // 512
    float* E3   = ws + 16896;      // 8192
    float* Z3   = ws + 25088;      // 512   (zeroed region ends at 25600)
    float* v1   = ws + 25600;      // 8192
    float* vsum = ws + 33792;      // 8192

    hipMemsetAsync(ws, 0, 25600 * sizeof(float), stream);

    // iter 1: S = sum_r u (uniform routing), W pass 1 (forward r)
    k_route<0, 0><<<dim3(64, 16), 512, 0, stream>>>(W, x, v1, E1, Z2);
    k_v1<<<32, 256, 0, stream>>>(E1, v1);          // v1 = squash(S/R)

    // iter 2: logits = <u, v1>, W pass 2 (reverse r for L3 tail reuse)
    k_route<1, 1><<<dim3(64, 16), 512, 0, stream>>>(W, x, v1, E2, Z2);
    k_vsum<<<32, 256, 0, stream>>>(E2, Z2, v1, vsum);  // vsum = v1 + squash(E2/Z2)

    // iter 3: logits = <u, v1+v2>, W pass 3 (forward r)
    k_route<1, 0><<<dim3(64, 16), 512, 0, stream>>>(W, x, vsum, E3, Z3);
    k_vout<<<32, 256, 0, stream>>>(E3, Z3, out);
}